// Round 3
// baseline (459.462 us; speedup 1.0000x reference)
//
#include <hip/hip_runtime.h>
#include <math.h>

// Problem constants
#define B 128
#define T 1024
#define H 512
#define L 2
#define G3H 1536   // 3*H
#define C 8        // attention T-chunks (grid.x)
#define TC 128     // T per chunk
#define TT 8       // t-tile staged in LDS (16 KB)
#define NT (TC / TT)
#define KS 4       // GEMM split-K factor

#define GLOBAL_AS __attribute__((address_space(1)))
#define LDS_AS    __attribute__((address_space(3)))

// ---------------------------------------------------------------------------
// Fused attention: score + online-softmax + weighted-sum in ONE enc pass.
// grid (C, B) x 256. Async double-buffered global_load_lds staging:
//   loop top __syncthreads() drains vmcnt -> tile t ready;
//   then issue prefetch of tile t+1 (overlaps full compute of tile t);
//   mid-tile score handoff uses lgkm-only wait + raw s_barrier so the
//   prefetch stays in flight across it.
// hidden@w_h and attn_b are constant over t -> cancel under softmax.
__global__ __launch_bounds__(256, 4)
void attn_fused_kernel(const float* __restrict__ enc,
                       const float* __restrict__ attn_w,
                       float* __restrict__ score_out,
                       float* __restrict__ part,
                       float* __restrict__ stats) {
    int c = blockIdx.x, b = blockIdx.y;
    int tid = threadIdx.x, lane = tid & 63, wave = tid >> 6;
    __shared__ float tile[2][TT * H];     // 2 x 16 KB
    __shared__ float s_tile[TT];

    // lane's 8 w_e coeffs, contiguous (cols lane*8 .. lane*8+7)
    const float4 we0 = *(const float4*)(attn_w + L * H + lane * 8);
    const float4 we1 = *(const float4*)(attn_w + L * H + lane * 8 + 4);

    const float* encb = enc + ((size_t)b * T + c * TC) * H;
    const GLOBAL_AS float* gsrc = (const GLOBAL_AS float*)encb;
    LDS_AS float* ldst = (LDS_AS float*)(&tile[0][0]);

    // stage tile t0 (TT*H floats = 16 KB) into buffer buf: 4 insts/thread,
    // each wave-instruction moves 1 KB contiguous (uniform base + lane*16).
#define STAGE(buf, t0)                                                        \
    {                                                                         \
        const GLOBAL_AS float* g = gsrc + (size_t)(t0) * H;                   \
        LDS_AS float* lb = ldst + (buf) * (TT * H);                           \
        _Pragma("unroll")                                                     \
        for (int k = 0; k < 4; k++) {                                         \
            __builtin_amdgcn_global_load_lds(                                 \
                (const GLOBAL_AS void*)(g + k * 1024 + tid * 4),              \
                (LDS_AS void*)(lb + k * 1024 + tid * 4), 16, 0, 0);           \
        }                                                                     \
    }

    float m_run = -1e30f, l_run = 0.0f;
    float accx = 0.0f, accy = 0.0f;

    STAGE(0, 0);
    for (int t = 0; t < NT; t++) {
        __syncthreads();   // drains own vmcnt -> tile t visible to all waves
        if (t + 1 < NT) STAGE((t + 1) & 1, (t + 1) * TT);
        const float* tb = &tile[t & 1][0];

        // scores: wave computes rows wave*2 .. wave*2+1 (2x ds_read_b128)
#pragma unroll
        for (int r = 0; r < 2; r++) {
            int row = wave * 2 + r;
            const float* tr = tb + row * H + lane * 8;
            float4 e0 = *(const float4*)(tr);
            float4 e1 = *(const float4*)(tr + 4);
            float d = e0.x * we0.x + e0.y * we0.y + e0.z * we0.z + e0.w * we0.w
                    + e1.x * we1.x + e1.y * we1.y + e1.z * we1.z + e1.w * we1.w;
#pragma unroll
            for (int off = 32; off; off >>= 1) d += __shfl_xor(d, off);
            if (lane == 0) {
                s_tile[row] = d;
                score_out[b * T + c * TC + t * TT + row] = d;
            }
        }
        // lgkm-only wait + raw barrier: prefetch (vmcnt) stays in flight
        __builtin_amdgcn_s_waitcnt(0xC07F);   // lgkmcnt(0), vmcnt=63, expcnt=7
        __builtin_amdgcn_s_barrier();

        // online-softmax update (thread-redundant, deterministic)
        float sarr[TT], tmax = -1e30f;
#pragma unroll
        for (int i = 0; i < TT; i++) {
            sarr[i] = s_tile[i];
            tmax = fmaxf(tmax, sarr[i]);
        }
        float m_new = fmaxf(m_run, tmax);
        float alpha = __expf(m_run - m_new);
        accx *= alpha; accy *= alpha;
        float wsum = 0.0f;
        // thread owns cols tid and tid+256 (2-way bank alias = free)
#pragma unroll
        for (int i = 0; i < TT; i++) {
            float w = __expf(sarr[i] - m_new);
            wsum += w;
            accx += w * tb[i * H + tid];
            accy += w * tb[i * H + tid + 256];
        }
        l_run = l_run * alpha + wsum;
        m_run = m_new;
    }
    part[((size_t)c * B + b) * H + tid]       = accx;
    part[((size_t)c * B + b) * H + tid + 256] = accy;
    if (tid == 0) {
        stats[(c * B + b) * 2]     = m_run;
        stats[(c * B + b) * 2 + 1] = l_run;
    }
#undef STAGE
}

// ---------------------------------------------------------------------------
// Combine chunk partials -> attn_applied; emit normalized attn_weights.
// grid B x 256.
__global__ void attn_reduce_kernel(const float* __restrict__ part,
                                   const float* __restrict__ stats,
                                   const float* __restrict__ score,
                                   float* __restrict__ attn_applied,
                                   float* __restrict__ attnw) {
    int b = blockIdx.x, tid = threadIdx.x;
    float mc[C], lc[C], m_fin = -1e30f;
#pragma unroll
    for (int k = 0; k < C; k++) {
        mc[k] = stats[(k * B + b) * 2];
        lc[k] = stats[(k * B + b) * 2 + 1];
        m_fin = fmaxf(m_fin, mc[k]);
    }
    float l_fin = 0.0f;
#pragma unroll
    for (int k = 0; k < C; k++) l_fin += lc[k] * __expf(mc[k] - m_fin);
    float inv = 1.0f / l_fin;
    float ax = 0.0f, ay = 0.0f;
#pragma unroll
    for (int k = 0; k < C; k++) {
        float sc = __expf(mc[k] - m_fin);
        ax += sc * part[((size_t)k * B + b) * H + tid];
        ay += sc * part[((size_t)k * B + b) * H + tid + 256];
    }
    attn_applied[(size_t)b * H + tid]       = ax * inv;
    attn_applied[(size_t)b * H + tid + 256] = ay * inv;
    float4 sv = *(const float4*)(score + b * T + tid * 4);
    float4 ov = { __expf(sv.x - m_fin) * inv, __expf(sv.y - m_fin) * inv,
                  __expf(sv.z - m_fin) * inv, __expf(sv.w - m_fin) * inv };
    *(float4*)(attnw + b * T + tid * 4) = ov;
}

// ---------------------------------------------------------------------------
// x[b,h] = relu(in0[b]*comb_w[h,0] + attn[b,:]·comb_w[h,1:] + comb_b[h])
// grid (4, B) x 256; wave-per-row dots.
__global__ void comb_kernel(const float* __restrict__ attn_applied,
                            const float* __restrict__ input,
                            const float* __restrict__ comb_w,
                            const float* __restrict__ comb_b,
                            float* __restrict__ x_out) {
    int q = blockIdx.x, b = blockIdx.y, tid = threadIdx.x;
    int lane = tid & 63, wave = tid >> 6;
    float in0 = input[b * 8 + 7];     // input[:, -1], block-uniform
    float areg[8];
#pragma unroll
    for (int j = 0; j < 8; j++) areg[j] = attn_applied[(size_t)b * H + j * 64 + lane];
    for (int r = 0; r < 32; r++) {
        int h = q * 128 + wave * 32 + r;
        const float* wr = comb_w + (size_t)h * (H + 1);
        float d = 0.0f;
#pragma unroll
        for (int j = 0; j < 8; j++) d += areg[j] * wr[1 + j * 64 + lane];
#pragma unroll
        for (int off = 32; off; off >>= 1) d += __shfl_xor(d, off);
        if (lane == 0)
            x_out[(size_t)b * H + h] = fmaxf(0.0f, d + in0 * wr[0] + comb_b[h]);
    }
}

// ---------------------------------------------------------------------------
// C = A @ W^T, split-K. A:(B x H), W:(3H x H), C-partials:(KS x B x 3H).
// grid (48, 4, 2*KS): z = ks*2 + sel, sel picks (x,w_ih,gx) vs (hidden,w_hh,gh).
__global__ void gemm_kernel(const float* __restrict__ A0,
                            const float* __restrict__ A1,
                            const float* __restrict__ W0,
                            const float* __restrict__ W1,
                            float* __restrict__ C0,
                            float* __restrict__ C1) {
    int z = blockIdx.z;
    int sel = z & 1, ks = z >> 1;
    const float* A = sel ? A1 : A0;
    const float* W = sel ? W1 : W0;
    float* Cp = (sel ? C1 : C0) + (size_t)ks * B * G3H;
    __shared__ float As[32][33];
    __shared__ float Ws[32][33];
    int n0 = blockIdx.x * 32, m0 = blockIdx.y * 32;
    int tid = threadIdx.x;
    int lrow = tid >> 3;            // 0..31
    int lcol = (tid & 7) * 4;       // 0,4,..,28
    int tm = (tid >> 4) * 2;        // 0..30 even
    int tn = (tid & 15) * 2;
    float a00 = 0, a01 = 0, a10 = 0, a11 = 0;
    int kbeg = ks * (H / KS), kend = kbeg + H / KS;
    for (int k0 = kbeg; k0 < kend; k0 += 32) {
        float4 av = *(const float4*)(A + (size_t)(m0 + lrow) * H + k0 + lcol);
        float4 wv = *(const float4*)(W + (size_t)(n0 + lrow) * H + k0 + lcol);
        __syncthreads();
        As[lrow][lcol] = av.x; As[lrow][lcol + 1] = av.y;
        As[lrow][lcol + 2] = av.z; As[lrow][lcol + 3] = av.w;
        Ws[lrow][lcol] = wv.x; Ws[lrow][lcol + 1] = wv.y;
        Ws[lrow][lcol + 2] = wv.z; Ws[lrow][lcol + 3] = wv.w;
        __syncthreads();
#pragma unroll
        for (int k = 0; k < 32; k++) {
            float x0 = As[tm][k], x1 = As[tm + 1][k];
            float w0 = Ws[tn][k], w1 = Ws[tn + 1][k];
            a00 += x0 * w0; a01 += x0 * w1;
            a10 += x1 * w0; a11 += x1 * w1;
        }
    }
    Cp[(size_t)(m0 + tm) * G3H + n0 + tn]         = a00;
    Cp[(size_t)(m0 + tm) * G3H + n0 + tn + 1]     = a01;
    Cp[(size_t)(m0 + tm + 1) * G3H + n0 + tn]     = a10;
    Cp[(size_t)(m0 + tm + 1) * G3H + n0 + tn + 1] = a11;
}

// ---------------------------------------------------------------------------
// GRU gate combine; sums KS split-K partials. grid 256 x 256.
__global__ void gates_kernel(const float* __restrict__ gx,
                             const float* __restrict__ gh,
                             const float* __restrict__ b_ih,
                             const float* __restrict__ b_hh,
                             const float* __restrict__ hprev,
                             float* __restrict__ hid_out,
                             float* __restrict__ x_out) {
    int idx = blockIdx.x * 256 + threadIdx.x;   // 0..65535
    int b = idx >> 9, h = idx & 511;
    size_t gb = (size_t)b * G3H;
    float xr = b_ih[h], xz = b_ih[H + h], xn = b_ih[2 * H + h];
    float hr = b_hh[h], hz = b_hh[H + h], hn = b_hh[2 * H + h];
#pragma unroll
    for (int k = 0; k < KS; k++) {
        size_t o = (size_t)k * B * G3H + gb;
        xr += gx[o + h];         xz += gx[o + H + h];     xn += gx[o + 2 * H + h];
        hr += gh[o + h];         hz += gh[o + H + h];     hn += gh[o + 2 * H + h];
    }
    float hp = hprev[(size_t)b * H + h];
    float r = 1.0f / (1.0f + expf(-(xr + hr)));
    float z = 1.0f / (1.0f + expf(-(xz + hz)));
    float n = tanhf(xn + r * hn);
    float hnew = (1.0f - z) * n + z * hp;
    hid_out[(size_t)b * H + h] = hnew;
    x_out[(size_t)b * H + h] = hnew;
}

// ---------------------------------------------------------------------------
// output[b] = dot(x[b], out_w) + out_b. grid B x 64.
__global__ void out_kernel(const float* __restrict__ x,
                           const float* __restrict__ out_w,
                           const float* __restrict__ out_b,
                           float* __restrict__ out) {
    int b = blockIdx.x, lane = threadIdx.x;
    const float4 w0 = *(const float4*)(out_w + lane * 8);
    const float4 w1 = *(const float4*)(out_w + lane * 8 + 4);
    const float4 x0 = *(const float4*)(x + (size_t)b * H + lane * 8);
    const float4 x1 = *(const float4*)(x + (size_t)b * H + lane * 8 + 4);
    float d = x0.x * w0.x + x0.y * w0.y + x0.z * w0.z + x0.w * w0.w
            + x1.x * w1.x + x1.y * w1.y + x1.z * w1.z + x1.w * w1.w;
#pragma unroll
    for (int off = 32; off; off >>= 1) d += __shfl_xor(d, off);
    if (lane == 0) out[b] = d + out_b[0];
}

// ---------------------------------------------------------------------------
extern "C" void kernel_launch(void* const* d_in, const int* in_sizes, int n_in,
                              void* d_out, int out_size, void* d_ws, size_t ws_size,
                              hipStream_t stream) {
    const float* input  = (const float*)d_in[0];
    const float* hidden = (const float*)d_in[1];
    const float* enc    = (const float*)d_in[2];
    const float* attn_w = (const float*)d_in[3];
    // d_in[4] = attn_b: cancels under softmax
    const float* comb_w = (const float*)d_in[5];
    const float* comb_b = (const float*)d_in[6];
    const float* w_ih   = (const float*)d_in[7];
    const float* w_hh   = (const float*)d_in[8];
    const float* b_ih   = (const float*)d_in[9];
    const float* b_hh   = (const float*)d_in[10];
    const float* out_w  = (const float*)d_in[11];
    const float* out_b  = (const float*)d_in[12];

    float* out = (float*)d_out;
    // d_out layout: output[128] | hidden_out[L*B*H] | attn_weights[B*T]
    float* hid_out = out + B;
    float* attnw   = out + B + L * B * H;

    float* ws      = (float*)d_ws;
    float* score   = ws;                       // B*T          = 131072
    float* part    = score + B * T;            // C*B*H        = 524288
    float* stats   = part + C * B * H;         // C*B*2        = 2048
    float* attnapp = stats + C * B * 2;        // B*H          = 65536
    float* x       = attnapp + B * H;          // B*H          = 65536
    float* gx      = x + B * H;                // KS*B*3H      = 786432
    float* gh      = gx + KS * B * G3H;        // KS*B*3H      = 786432

    attn_fused_kernel<<<dim3(C, B), 256, 0, stream>>>(enc, attn_w, score, part, stats);
    attn_reduce_kernel<<<dim3(B), 256, 0, stream>>>(part, stats, score, attnapp, attnw);
    comb_kernel<<<dim3(4, B), 256, 0, stream>>>(attnapp, input, comb_w, comb_b, x);

    for (int l = 0; l < L; l++) {
        const float* hl = hidden + (size_t)l * B * H;
        gemm_kernel<<<dim3(G3H / 32, B / 32, 2 * KS), 256, 0, stream>>>(
            x, hl,
            w_ih + (size_t)l * G3H * H, w_hh + (size_t)l * G3H * H,
            gx, gh);
        gates_kernel<<<dim3(B * H / 256), 256, 0, stream>>>(
            gx, gh, b_ih + l * G3H, b_hh + l * G3H, hl,
            hid_out + (size_t)l * B * H, x);
    }
    out_kernel<<<dim3(B), 64, 0, stream>>>(x, out_w, out_b, out);
}

// Round 4
// 445.449 us; speedup vs baseline: 1.0315x; 1.0315x over previous
//
#include <hip/hip_runtime.h>
#include <math.h>

// Problem constants
#define B 128
#define T 1024
#define H 512
#define L 2
#define G3H 1536   // 3*H
#define C 8        // attention T-chunks (grid.x)
#define TC 128     // T per chunk
#define TT 8       // t-tile staged in LDS (16 KB)
#define NT (TC / TT)
#define KS 2       // GEMM split-K factor

#define GLOBAL_AS __attribute__((address_space(1)))
#define LDS_AS    __attribute__((address_space(3)))

typedef __attribute__((ext_vector_type(8))) short bf16x8;
typedef __attribute__((ext_vector_type(4))) float f32x4;

// ---------------------------------------------------------------------------
// Fused attention: score + online-softmax + weighted-sum in ONE enc pass.
// grid (C, B) x 256. Async double-buffered global_load_lds staging.
// hidden@w_h and attn_b are constant over t -> cancel under softmax.
__global__ __launch_bounds__(256, 4)
void attn_fused_kernel(const float* __restrict__ enc,
                       const float* __restrict__ attn_w,
                       float* __restrict__ score_out,
                       float* __restrict__ part,
                       float* __restrict__ stats) {
    int c = blockIdx.x, b = blockIdx.y;
    int tid = threadIdx.x, lane = tid & 63, wave = tid >> 6;
    __shared__ float tile[2][TT * H];     // 2 x 16 KB
    __shared__ float s_tile[TT];

    const float4 we0 = *(const float4*)(attn_w + L * H + lane * 8);
    const float4 we1 = *(const float4*)(attn_w + L * H + lane * 8 + 4);

    const float* encb = enc + ((size_t)b * T + c * TC) * H;
    const GLOBAL_AS float* gsrc = (const GLOBAL_AS float*)encb;
    LDS_AS float* ldst = (LDS_AS float*)(&tile[0][0]);

#define STAGE(buf, t0)                                                        \
    {                                                                         \
        const GLOBAL_AS float* g = gsrc + (size_t)(t0) * H;                   \
        LDS_AS float* lb = ldst + (buf) * (TT * H);                           \
        _Pragma("unroll")                                                     \
        for (int k = 0; k < 4; k++) {                                         \
            __builtin_amdgcn_global_load_lds(                                 \
                (const GLOBAL_AS void*)(g + k * 1024 + tid * 4),              \
                (LDS_AS void*)(lb + k * 1024 + tid * 4), 16, 0, 0);           \
        }                                                                     \
    }

    float m_run = -1e30f, l_run = 0.0f;
    float accx = 0.0f, accy = 0.0f;

    STAGE(0, 0);
    for (int t = 0; t < NT; t++) {
        __syncthreads();   // drains own vmcnt -> tile t visible to all waves
        if (t + 1 < NT) STAGE((t + 1) & 1, (t + 1) * TT);
        const float* tb = &tile[t & 1][0];

#pragma unroll
        for (int r = 0; r < 2; r++) {
            int row = wave * 2 + r;
            const float* tr = tb + row * H + lane * 8;
            float4 e0 = *(const float4*)(tr);
            float4 e1 = *(const float4*)(tr + 4);
            float d = e0.x * we0.x + e0.y * we0.y + e0.z * we0.z + e0.w * we0.w
                    + e1.x * we1.x + e1.y * we1.y + e1.z * we1.z + e1.w * we1.w;
#pragma unroll
            for (int off = 32; off; off >>= 1) d += __shfl_xor(d, off);
            if (lane == 0) {
                s_tile[row] = d;
                score_out[b * T + c * TC + t * TT + row] = d;
            }
        }
        // lgkm-only wait + raw barrier: prefetch (vmcnt) stays in flight
        __builtin_amdgcn_s_waitcnt(0xC07F);
        __builtin_amdgcn_s_barrier();

        float sarr[TT], tmax = -1e30f;
#pragma unroll
        for (int i = 0; i < TT; i++) {
            sarr[i] = s_tile[i];
            tmax = fmaxf(tmax, sarr[i]);
        }
        float m_new = fmaxf(m_run, tmax);
        float alpha = __expf(m_run - m_new);
        accx *= alpha; accy *= alpha;
        float wsum = 0.0f;
#pragma unroll
        for (int i = 0; i < TT; i++) {
            float w = __expf(sarr[i] - m_new);
            wsum += w;
            accx += w * tb[i * H + tid];
            accy += w * tb[i * H + tid + 256];
        }
        l_run = l_run * alpha + wsum;
        m_run = m_new;
    }
    part[((size_t)c * B + b) * H + tid]       = accx;
    part[((size_t)c * B + b) * H + tid + 256] = accy;
    if (tid == 0) {
        stats[(c * B + b) * 2]     = m_run;
        stats[(c * B + b) * 2 + 1] = l_run;
    }
#undef STAGE
}

// ---------------------------------------------------------------------------
// Combine chunk partials -> attn_applied; emit normalized attn_weights.
// grid B x 256.
__global__ void attn_reduce_kernel(const float* __restrict__ part,
                                   const float* __restrict__ stats,
                                   const float* __restrict__ score,
                                   float* __restrict__ attn_applied,
                                   float* __restrict__ attnw) {
    int b = blockIdx.x, tid = threadIdx.x;
    float mc[C], lc[C], m_fin = -1e30f;
#pragma unroll
    for (int k = 0; k < C; k++) {
        mc[k] = stats[(k * B + b) * 2];
        lc[k] = stats[(k * B + b) * 2 + 1];
        m_fin = fmaxf(m_fin, mc[k]);
    }
    float l_fin = 0.0f;
#pragma unroll
    for (int k = 0; k < C; k++) l_fin += lc[k] * __expf(mc[k] - m_fin);
    float inv = 1.0f / l_fin;
    float ax = 0.0f, ay = 0.0f;
#pragma unroll
    for (int k = 0; k < C; k++) {
        float sc = __expf(mc[k] - m_fin);
        ax += sc * part[((size_t)k * B + b) * H + tid];
        ay += sc * part[((size_t)k * B + b) * H + tid + 256];
    }
    attn_applied[(size_t)b * H + tid]       = ax * inv;
    attn_applied[(size_t)b * H + tid + 256] = ay * inv;
    float4 sv = *(const float4*)(score + b * T + tid * 4);
    float4 ov = { __expf(sv.x - m_fin) * inv, __expf(sv.y - m_fin) * inv,
                  __expf(sv.z - m_fin) * inv, __expf(sv.w - m_fin) * inv };
    *(float4*)(attnw + b * T + tid * 4) = ov;
}

// ---------------------------------------------------------------------------
// x[b,h] = relu(in0[b]*comb_w[h,0] + attn[b,:]·comb_w[h,1:] + comb_b[h])
// grid (4, B) x 256; wave-per-row dots.
__global__ void comb_kernel(const float* __restrict__ attn_applied,
                            const float* __restrict__ input,
                            const float* __restrict__ comb_w,
                            const float* __restrict__ comb_b,
                            float* __restrict__ x_out) {
    int q = blockIdx.x, b = blockIdx.y, tid = threadIdx.x;
    int lane = tid & 63, wave = tid >> 6;
    float in0 = input[b * 8 + 7];     // input[:, -1], block-uniform
    float areg[8];
#pragma unroll
    for (int j = 0; j < 8; j++) areg[j] = attn_applied[(size_t)b * H + j * 64 + lane];
    for (int r = 0; r < 32; r++) {
        int h = q * 128 + wave * 32 + r;
        const float* wr = comb_w + (size_t)h * (H + 1);
        float d = 0.0f;
#pragma unroll
        for (int j = 0; j < 8; j++) d += areg[j] * wr[1 + j * 64 + lane];
#pragma unroll
        for (int off = 32; off; off >>= 1) d += __shfl_xor(d, off);
        if (lane == 0)
            x_out[(size_t)b * H + h] = fmaxf(0.0f, d + in0 * wr[0] + comb_b[h]);
    }
}

// ---------------------------------------------------------------------------
// MFMA bf16 wave-GEMM, direct from global (no LDS).
// C = A @ W^T. A:(B x H) f32, W:(3H x H) f32, C-partials:(KS x B x 3H) f32.
// One wave per job: job = nt(96) x mh(2) x ks(KS) x sel(2).
// Wave computes a 64(m) x 16(n) strip over a K-half of 256.
// Layouts (m89/m120 verified): A-frag A[m=lane&15][k=quad*8+j];
// B-frag = W[n=lane&15][k=quad*8+j]; C/D col=lane&15, row=quad*4+reg.
__device__ inline short f2bf(float f) {
    union { float f; unsigned u; } v; v.f = f;
    unsigned r = v.u + 0x7fffu + ((v.u >> 16) & 1u);   // RNE
    return (short)(r >> 16);
}

__device__ inline bf16x8 load_frag(const float* __restrict__ p) {
    float4 a = *(const float4*)p;
    float4 b = *(const float4*)(p + 4);
    bf16x8 r;
    r[0] = f2bf(a.x); r[1] = f2bf(a.y); r[2] = f2bf(a.z); r[3] = f2bf(a.w);
    r[4] = f2bf(b.x); r[5] = f2bf(b.y); r[6] = f2bf(b.z); r[7] = f2bf(b.w);
    return r;
}

__global__ __launch_bounds__(64)
void gemm_mfma_kernel(const float* __restrict__ A0,
                      const float* __restrict__ A1,
                      const float* __restrict__ W0,
                      const float* __restrict__ W1,
                      float* __restrict__ C0,
                      float* __restrict__ C1) {
    int job = blockIdx.x;
    int sel = job & 1, ks = (job >> 1) & (KS - 1), mh = (job >> 2) & 1, nt = job >> 3;
    const float* A = sel ? A1 : A0;
    const float* W = sel ? W1 : W0;
    float* Cp = (sel ? C1 : C0) + (size_t)ks * B * G3H;
    int lane = threadIdx.x;
    int row16 = lane & 15, quad = lane >> 4;
    int n0 = nt * 16, m0 = mh * 64;
    int kb = ks * (H / KS);
    const float* Wp = W + (size_t)(n0 + row16) * H + kb + quad * 8;
    const float* Ap = A + (size_t)(m0 + row16) * H + kb + quad * 8;
    f32x4 acc0 = {0.f, 0.f, 0.f, 0.f}, acc1 = acc0, acc2 = acc0, acc3 = acc0;
#pragma unroll 2
    for (int k = 0; k < H / KS; k += 32) {
        bf16x8 bw = load_frag(Wp + k);
        bf16x8 a0 = load_frag(Ap + k);
        bf16x8 a1 = load_frag(Ap + 16 * H + k);
        bf16x8 a2 = load_frag(Ap + 32 * H + k);
        bf16x8 a3 = load_frag(Ap + 48 * H + k);
        acc0 = __builtin_amdgcn_mfma_f32_16x16x32_bf16(a0, bw, acc0, 0, 0, 0);
        acc1 = __builtin_amdgcn_mfma_f32_16x16x32_bf16(a1, bw, acc1, 0, 0, 0);
        acc2 = __builtin_amdgcn_mfma_f32_16x16x32_bf16(a2, bw, acc2, 0, 0, 0);
        acc3 = __builtin_amdgcn_mfma_f32_16x16x32_bf16(a3, bw, acc3, 0, 0, 0);
    }
    int col = n0 + row16;
    int rb = m0 + quad * 4;
#pragma unroll
    for (int reg = 0; reg < 4; reg++) {
        Cp[(size_t)(rb + reg) * G3H + col]      = acc0[reg];
        Cp[(size_t)(rb + 16 + reg) * G3H + col] = acc1[reg];
        Cp[(size_t)(rb + 32 + reg) * G3H + col] = acc2[reg];
        Cp[(size_t)(rb + 48 + reg) * G3H + col] = acc3[reg];
    }
}

// ---------------------------------------------------------------------------
// GRU gate combine; sums KS split-K partials. grid 256 x 256.
__global__ void gates_kernel(const float* __restrict__ gx,
                             const float* __restrict__ gh,
                             const float* __restrict__ b_ih,
                             const float* __restrict__ b_hh,
                             const float* __restrict__ hprev,
                             float* __restrict__ hid_out,
                             float* __restrict__ x_out) {
    int idx = blockIdx.x * 256 + threadIdx.x;   // 0..65535
    int b = idx >> 9, h = idx & 511;
    size_t gb = (size_t)b * G3H;
    float xr = b_ih[h], xz = b_ih[H + h], xn = b_ih[2 * H + h];
    float hr = b_hh[h], hz = b_hh[H + h], hn = b_hh[2 * H + h];
#pragma unroll
    for (int k = 0; k < KS; k++) {
        size_t o = (size_t)k * B * G3H + gb;
        xr += gx[o + h];         xz += gx[o + H + h];     xn += gx[o + 2 * H + h];
        hr += gh[o + h];         hz += gh[o + H + h];     hn += gh[o + 2 * H + h];
    }
    float hp = hprev[(size_t)b * H + h];
    float r = 1.0f / (1.0f + expf(-(xr + hr)));
    float z = 1.0f / (1.0f + expf(-(xz + hz)));
    float n = tanhf(xn + r * hn);
    float hnew = (1.0f - z) * n + z * hp;
    hid_out[(size_t)b * H + h] = hnew;
    x_out[(size_t)b * H + h] = hnew;
}

// ---------------------------------------------------------------------------
// output[b] = dot(x[b], out_w) + out_b. grid B x 64.
__global__ void out_kernel(const float* __restrict__ x,
                           const float* __restrict__ out_w,
                           const float* __restrict__ out_b,
                           float* __restrict__ out) {
    int b = blockIdx.x, lane = threadIdx.x;
    const float4 w0 = *(const float4*)(out_w + lane * 8);
    const float4 w1 = *(const float4*)(out_w + lane * 8 + 4);
    const float4 x0 = *(const float4*)(x + (size_t)b * H + lane * 8);
    const float4 x1 = *(const float4*)(x + (size_t)b * H + lane * 8 + 4);
    float d = x0.x * w0.x + x0.y * w0.y + x0.z * w0.z + x0.w * w0.w
            + x1.x * w1.x + x1.y * w1.y + x1.z * w1.z + x1.w * w1.w;
#pragma unroll
    for (int off = 32; off; off >>= 1) d += __shfl_xor(d, off);
    if (lane == 0) out[b] = d + out_b[0];
}

// ---------------------------------------------------------------------------
extern "C" void kernel_launch(void* const* d_in, const int* in_sizes, int n_in,
                              void* d_out, int out_size, void* d_ws, size_t ws_size,
                              hipStream_t stream) {
    const float* input  = (const float*)d_in[0];
    const float* hidden = (const float*)d_in[1];
    const float* enc    = (const float*)d_in[2];
    const float* attn_w = (const float*)d_in[3];
    // d_in[4] = attn_b: cancels under softmax
    const float* comb_w = (const float*)d_in[5];
    const float* comb_b = (const float*)d_in[6];
    const float* w_ih   = (const float*)d_in[7];
    const float* w_hh   = (const float*)d_in[8];
    const float* b_ih   = (const float*)d_in[9];
    const float* b_hh   = (const float*)d_in[10];
    const float* out_w  = (const float*)d_in[11];
    const float* out_b  = (const float*)d_in[12];

    float* out = (float*)d_out;
    // d_out layout: output[128] | hidden_out[L*B*H] | attn_weights[B*T]
    float* hid_out = out + B;
    float* attnw   = out + B + L * B * H;

    float* ws      = (float*)d_ws;
    float* score   = ws;                       // B*T          = 131072
    float* part    = score + B * T;            // C*B*H        = 524288
    float* stats   = part + C * B * H;         // C*B*2        = 2048
    float* attnapp = stats + C * B * 2;        // B*H          = 65536
    float* x       = attnapp + B * H;          // B*H          = 65536
    float* gx      = x + B * H;                // KS*B*3H
    float* gh      = gx + KS * B * G3H;        // KS*B*3H

    attn_fused_kernel<<<dim3(C, B), 256, 0, stream>>>(enc, attn_w, score, part, stats);
    attn_reduce_kernel<<<dim3(B), 256, 0, stream>>>(part, stats, score, attnapp, attnw);
    comb_kernel<<<dim3(4, B), 256, 0, stream>>>(attnapp, input, comb_w, comb_b, x);

    for (int l = 0; l < L; l++) {
        const float* hl = hidden + (size_t)l * B * H;
        // jobs = nt(96) x mh(2) x ks(KS) x sel(2), one wave each
        gemm_mfma_kernel<<<dim3((G3H / 16) * 2 * KS * 2), 64, 0, stream>>>(
            x, hl,
            w_ih + (size_t)l * G3H * H, w_hh + (size_t)l * G3H * H,
            gx, gh);
        gates_kernel<<<dim3(B * H / 256), 256, 0, stream>>>(
            gx, gh, b_ih + l * G3H, b_hh + l * G3H, hl,
            hid_out + (size_t)l * B * H, x);
    }
    out_kernel<<<dim3(B), 64, 0, stream>>>(x, out_w, out_b, out);
}

// Round 5
// 441.880 us; speedup vs baseline: 1.0398x; 1.0081x over previous
//
#include <hip/hip_runtime.h>
#include <math.h>

// Problem constants
#define B 128
#define T 1024
#define H 512
#define L 2
#define G3H 1536   // 3*H
#define C 8        // attention T-chunks (grid.x)
#define TC 128     // T per chunk
#define TT 8       // t-tile staged in LDS (16 KB)
#define NT (TC / TT)
#define KS 2       // GEMM split-K factor

#define GLOBAL_AS __attribute__((address_space(1)))
#define LDS_AS    __attribute__((address_space(3)))

typedef __attribute__((ext_vector_type(8))) short bf16x8;
typedef __attribute__((ext_vector_type(4))) float f32x4;

// ---------------------------------------------------------------------------
// Fused attention: score + online-softmax + weighted-sum in ONE enc pass.
// grid (C, B) x 256. Async double-buffered global_load_lds staging.
// hidden@w_h and attn_b are constant over t -> cancel under softmax.
__global__ __launch_bounds__(256, 4)
void attn_fused_kernel(const float* __restrict__ enc,
                       const float* __restrict__ attn_w,
                       float* __restrict__ score_out,
                       float* __restrict__ part,
                       float* __restrict__ stats) {
    int c = blockIdx.x, b = blockIdx.y;
    int tid = threadIdx.x, lane = tid & 63, wave = tid >> 6;
    __shared__ float tile[2][TT * H];     // 2 x 16 KB
    __shared__ float s_tile[TT];

    const float4 we0 = *(const float4*)(attn_w + L * H + lane * 8);
    const float4 we1 = *(const float4*)(attn_w + L * H + lane * 8 + 4);

    const float* encb = enc + ((size_t)b * T + c * TC) * H;
    const GLOBAL_AS float* gsrc = (const GLOBAL_AS float*)encb;
    LDS_AS float* ldst = (LDS_AS float*)(&tile[0][0]);

#define STAGE(buf, t0)                                                        \
    {                                                                         \
        const GLOBAL_AS float* g = gsrc + (size_t)(t0) * H;                   \
        LDS_AS float* lb = ldst + (buf) * (TT * H);                           \
        _Pragma("unroll")                                                     \
        for (int k = 0; k < 4; k++) {                                         \
            __builtin_amdgcn_global_load_lds(                                 \
                (const GLOBAL_AS void*)(g + k * 1024 + tid * 4),              \
                (LDS_AS void*)(lb + k * 1024 + tid * 4), 16, 0, 0);           \
        }                                                                     \
    }

    float m_run = -1e30f, l_run = 0.0f;
    float accx = 0.0f, accy = 0.0f;

    STAGE(0, 0);
    for (int t = 0; t < NT; t++) {
        __syncthreads();   // drains own vmcnt -> tile t visible to all waves
        if (t + 1 < NT) STAGE((t + 1) & 1, (t + 1) * TT);
        const float* tb = &tile[t & 1][0];

#pragma unroll
        for (int r = 0; r < 2; r++) {
            int row = wave * 2 + r;
            const float* tr = tb + row * H + lane * 8;
            float4 e0 = *(const float4*)(tr);
            float4 e1 = *(const float4*)(tr + 4);
            float d = e0.x * we0.x + e0.y * we0.y + e0.z * we0.z + e0.w * we0.w
                    + e1.x * we1.x + e1.y * we1.y + e1.z * we1.z + e1.w * we1.w;
#pragma unroll
            for (int off = 32; off; off >>= 1) d += __shfl_xor(d, off);
            if (lane == 0) {
                s_tile[row] = d;
                score_out[b * T + c * TC + t * TT + row] = d;
            }
        }
        // lgkm-only wait + raw barrier: prefetch (vmcnt) stays in flight
        __builtin_amdgcn_s_waitcnt(0xC07F);
        __builtin_amdgcn_s_barrier();

        float sarr[TT], tmax = -1e30f;
#pragma unroll
        for (int i = 0; i < TT; i++) {
            sarr[i] = s_tile[i];
            tmax = fmaxf(tmax, sarr[i]);
        }
        float m_new = fmaxf(m_run, tmax);
        float alpha = __expf(m_run - m_new);
        accx *= alpha; accy *= alpha;
        float wsum = 0.0f;
#pragma unroll
        for (int i = 0; i < TT; i++) {
            float w = __expf(sarr[i] - m_new);
            wsum += w;
            accx += w * tb[i * H + tid];
            accy += w * tb[i * H + tid + 256];
        }
        l_run = l_run * alpha + wsum;
        m_run = m_new;
    }
    part[((size_t)c * B + b) * H + tid]       = accx;
    part[((size_t)c * B + b) * H + tid + 256] = accy;
    if (tid == 0) {
        stats[(c * B + b) * 2]     = m_run;
        stats[(c * B + b) * 2 + 1] = l_run;
    }
#undef STAGE
}

// ---------------------------------------------------------------------------
// Merged chunk-combine + comb layer.
// grid (4, B) x 256. Every block recomputes the (cheap) chunk reduction into
// LDS; q==0 additionally writes normalized attn_weights to d_out.
// x[b,h] = relu(in0[b]*comb_w[h,0] + attn[b,:]·comb_w[h,1:] + comb_b[h])
__global__ void comb_kernel(const float* __restrict__ part,
                            const float* __restrict__ stats,
                            const float* __restrict__ score,
                            const float* __restrict__ input,
                            const float* __restrict__ comb_w,
                            const float* __restrict__ comb_b,
                            float* __restrict__ x_out,
                            float* __restrict__ attnw) {
    int q = blockIdx.x, b = blockIdx.y, tid = threadIdx.x;
    int lane = tid & 63, wave = tid >> 6;
    __shared__ float at[H];

    // chunk-combine (online-softmax final merge)
    float mc[C], lc[C], m_fin = -1e30f;
#pragma unroll
    for (int k = 0; k < C; k++) {
        mc[k] = stats[(k * B + b) * 2];
        lc[k] = stats[(k * B + b) * 2 + 1];
        m_fin = fmaxf(m_fin, mc[k]);
    }
    float l_fin = 0.0f;
#pragma unroll
    for (int k = 0; k < C; k++) l_fin += lc[k] * __expf(mc[k] - m_fin);
    float inv = 1.0f / l_fin;
    float ax = 0.0f, ay = 0.0f;
#pragma unroll
    for (int k = 0; k < C; k++) {
        float sc = __expf(mc[k] - m_fin);
        ax += sc * part[((size_t)k * B + b) * H + tid];
        ay += sc * part[((size_t)k * B + b) * H + tid + 256];
    }
    at[tid]       = ax * inv;
    at[tid + 256] = ay * inv;
    if (q == 0) {
        float4 sv = *(const float4*)(score + b * T + tid * 4);
        float4 ov = { __expf(sv.x - m_fin) * inv, __expf(sv.y - m_fin) * inv,
                      __expf(sv.z - m_fin) * inv, __expf(sv.w - m_fin) * inv };
        *(float4*)(attnw + b * T + tid * 4) = ov;
    }
    __syncthreads();

    float in0 = input[b * 8 + 7];     // input[:, -1], block-uniform
    float areg[8];
#pragma unroll
    for (int j = 0; j < 8; j++) areg[j] = at[j * 64 + lane];  // 2-way = free
    for (int r = 0; r < 32; r++) {
        int h = q * 128 + wave * 32 + r;
        const float* wr = comb_w + (size_t)h * (H + 1);
        float d = 0.0f;
#pragma unroll
        for (int j = 0; j < 8; j++) d += areg[j] * wr[1 + j * 64 + lane];
#pragma unroll
        for (int off = 32; off; off >>= 1) d += __shfl_xor(d, off);
        if (lane == 0)
            x_out[(size_t)b * H + h] = fmaxf(0.0f, d + in0 * wr[0] + comb_b[h]);
    }
}

// ---------------------------------------------------------------------------
// MFMA bf16 wave-GEMM, direct from global (no LDS).
// C = A @ W^T. A:(B x H) f32, W:(3H x H) f32, C-partials:(KS x B x 3H) f32.
// One wave per job: job = nt(96) x mh(2) x ks(KS) x sel(2).
// Layouts (m89/m120 verified): A-frag A[m=lane&15][k=quad*8+j];
// B-frag = W[n=lane&15][k=quad*8+j]; C/D col=lane&15, row=quad*4+reg.
__device__ inline short f2bf(float f) {
    union { float f; unsigned u; } v; v.f = f;
    unsigned r = v.u + 0x7fffu + ((v.u >> 16) & 1u);   // RNE
    return (short)(r >> 16);
}

__device__ inline bf16x8 load_frag(const float* __restrict__ p) {
    float4 a = *(const float4*)p;
    float4 b = *(const float4*)(p + 4);
    bf16x8 r;
    r[0] = f2bf(a.x); r[1] = f2bf(a.y); r[2] = f2bf(a.z); r[3] = f2bf(a.w);
    r[4] = f2bf(b.x); r[5] = f2bf(b.y); r[6] = f2bf(b.z); r[7] = f2bf(b.w);
    return r;
}

__global__ __launch_bounds__(64)
void gemm_mfma_kernel(const float* __restrict__ A0,
                      const float* __restrict__ A1,
                      const float* __restrict__ W0,
                      const float* __restrict__ W1,
                      float* __restrict__ C0,
                      float* __restrict__ C1) {
    int job = blockIdx.x;
    int sel = job & 1, ks = (job >> 1) & (KS - 1), mh = (job >> 2) & 1, nt = job >> 3;
    const float* A = sel ? A1 : A0;
    const float* W = sel ? W1 : W0;
    float* Cp = (sel ? C1 : C0) + (size_t)ks * B * G3H;
    int lane = threadIdx.x;
    int row16 = lane & 15, quad = lane >> 4;
    int n0 = nt * 16, m0 = mh * 64;
    int kb = ks * (H / KS);
    const float* Wp = W + (size_t)(n0 + row16) * H + kb + quad * 8;
    const float* Ap = A + (size_t)(m0 + row16) * H + kb + quad * 8;
    f32x4 acc0 = {0.f, 0.f, 0.f, 0.f}, acc1 = acc0, acc2 = acc0, acc3 = acc0;
#pragma unroll 2
    for (int k = 0; k < H / KS; k += 32) {
        bf16x8 bw = load_frag(Wp + k);
        bf16x8 a0 = load_frag(Ap + k);
        bf16x8 a1 = load_frag(Ap + 16 * H + k);
        bf16x8 a2 = load_frag(Ap + 32 * H + k);
        bf16x8 a3 = load_frag(Ap + 48 * H + k);
        acc0 = __builtin_amdgcn_mfma_f32_16x16x32_bf16(a0, bw, acc0, 0, 0, 0);
        acc1 = __builtin_amdgcn_mfma_f32_16x16x32_bf16(a1, bw, acc1, 0, 0, 0);
        acc2 = __builtin_amdgcn_mfma_f32_16x16x32_bf16(a2, bw, acc2, 0, 0, 0);
        acc3 = __builtin_amdgcn_mfma_f32_16x16x32_bf16(a3, bw, acc3, 0, 0, 0);
    }
    int col = n0 + row16;
    int rb = m0 + quad * 4;
#pragma unroll
    for (int reg = 0; reg < 4; reg++) {
        Cp[(size_t)(rb + reg) * G3H + col]      = acc0[reg];
        Cp[(size_t)(rb + 16 + reg) * G3H + col] = acc1[reg];
        Cp[(size_t)(rb + 32 + reg) * G3H + col] = acc2[reg];
        Cp[(size_t)(rb + 48 + reg) * G3H + col] = acc3[reg];
    }
}

// ---------------------------------------------------------------------------
// GRU gate combine; sums KS split-K partials. grid B x 512 (one batch/block).
// When `last`, also computes output[b] = dot(hnew, out_w) + out_b in-block.
__global__ __launch_bounds__(512)
void gates_kernel(const float* __restrict__ gx,
                  const float* __restrict__ gh,
                  const float* __restrict__ b_ih,
                  const float* __restrict__ b_hh,
                  const float* __restrict__ hprev,
                  float* __restrict__ hid_out,
                  float* __restrict__ x_out,
                  const float* __restrict__ out_w,
                  const float* __restrict__ out_b,
                  float* __restrict__ out,
                  int last) {
    int b = blockIdx.x, h = threadIdx.x;
    int lane = h & 63, wave = h >> 6;
    size_t gb = (size_t)b * G3H;
    float xr = b_ih[h], xz = b_ih[H + h], xn = b_ih[2 * H + h];
    float hr = b_hh[h], hz = b_hh[H + h], hn = b_hh[2 * H + h];
#pragma unroll
    for (int k = 0; k < KS; k++) {
        size_t o = (size_t)k * B * G3H + gb;
        xr += gx[o + h];         xz += gx[o + H + h];     xn += gx[o + 2 * H + h];
        hr += gh[o + h];         hz += gh[o + H + h];     hn += gh[o + 2 * H + h];
    }
    float hp = hprev[(size_t)b * H + h];
    float r = 1.0f / (1.0f + expf(-(xr + hr)));
    float z = 1.0f / (1.0f + expf(-(xz + hz)));
    float n = tanhf(xn + r * hn);
    float hnew = (1.0f - z) * n + z * hp;
    hid_out[(size_t)b * H + h] = hnew;
    x_out[(size_t)b * H + h] = hnew;
    if (last) {
        __shared__ float red[8];
        float d = hnew * out_w[h];
#pragma unroll
        for (int off = 32; off; off >>= 1) d += __shfl_xor(d, off);
        if (lane == 0) red[wave] = d;
        __syncthreads();
        if (h == 0) {
            float s = out_b[0];
#pragma unroll
            for (int i = 0; i < 8; i++) s += red[i];
            out[b] = s;
        }
    }
}

// ---------------------------------------------------------------------------
extern "C" void kernel_launch(void* const* d_in, const int* in_sizes, int n_in,
                              void* d_out, int out_size, void* d_ws, size_t ws_size,
                              hipStream_t stream) {
    const float* input  = (const float*)d_in[0];
    const float* hidden = (const float*)d_in[1];
    const float* enc    = (const float*)d_in[2];
    const float* attn_w = (const float*)d_in[3];
    // d_in[4] = attn_b: cancels under softmax
    const float* comb_w = (const float*)d_in[5];
    const float* comb_b = (const float*)d_in[6];
    const float* w_ih   = (const float*)d_in[7];
    const float* w_hh   = (const float*)d_in[8];
    const float* b_ih   = (const float*)d_in[9];
    const float* b_hh   = (const float*)d_in[10];
    const float* out_w  = (const float*)d_in[11];
    const float* out_b  = (const float*)d_in[12];

    float* out = (float*)d_out;
    // d_out layout: output[128] | hidden_out[L*B*H] | attn_weights[B*T]
    float* hid_out = out + B;
    float* attnw   = out + B + L * B * H;

    float* ws      = (float*)d_ws;
    float* score   = ws;                       // B*T          = 131072
    float* part    = score + B * T;            // C*B*H        = 524288
    float* stats   = part + C * B * H;         // C*B*2        = 2048
    float* x       = stats + C * B * 2;        // B*H          = 65536
    float* gx      = x + B * H;                // KS*B*3H
    float* gh      = gx + KS * B * G3H;        // KS*B*3H

    attn_fused_kernel<<<dim3(C, B), 256, 0, stream>>>(enc, attn_w, score, part, stats);
    comb_kernel<<<dim3(4, B), 256, 0, stream>>>(part, stats, score, input,
                                                comb_w, comb_b, x, attnw);

    for (int l = 0; l < L; l++) {
        const float* hl = hidden + (size_t)l * B * H;
        // jobs = nt(96) x mh(2) x ks(KS) x sel(2), one wave each
        gemm_mfma_kernel<<<dim3((G3H / 16) * 2 * KS * 2), 64, 0, stream>>>(
            x, hl,
            w_ih + (size_t)l * G3H * H, w_hh + (size_t)l * G3H * H,
            gx, gh);
        gates_kernel<<<dim3(B), 512, 0, stream>>>(
            gx, gh, b_ih + l * G3H, b_hh + l * G3H, hl,
            hid_out + (size_t)l * B * H, x,
            out_w, out_b, out, l == L - 1);
    }
}